// Round 4
// baseline (337.464 us; speedup 1.0000x reference)
//
#include <hip/hip_runtime.h>
#include <math.h>

#define NF 128

typedef __attribute__((ext_vector_type(8))) short short8;
typedef __attribute__((ext_vector_type(4))) float floatx4;

__device__ __forceinline__ unsigned short f2bf(float f) {
    union { float x; unsigned int i; } c; c.x = f;
    unsigned int r = c.i + 0x7fffu + ((c.i >> 16) & 1u);   // RNE
    return (unsigned short)(r >> 16);
}
__device__ __forceinline__ float bf2f(unsigned short u) {
    union { unsigned int i; float x; } c; c.i = ((unsigned int)u) << 16;
    return c.x;
}
__device__ __forceinline__ void unpack8(uint4 u, float* f) {
    union { unsigned int i; float x; } c;
    c.i = u.x << 16;          f[0] = c.x;
    c.i = u.x & 0xffff0000u;  f[1] = c.x;
    c.i = u.y << 16;          f[2] = c.x;
    c.i = u.y & 0xffff0000u;  f[3] = c.x;
    c.i = u.z << 16;          f[4] = c.x;
    c.i = u.z & 0xffff0000u;  f[5] = c.x;
    c.i = u.w << 16;          f[6] = c.x;
    c.i = u.w & 0xffff0000u;  f[7] = c.x;
}
__device__ __forceinline__ ushort4 pack4(float a, float b, float c, float d) {
    ushort4 h; h.x = f2bf(a); h.y = f2bf(b); h.z = f2bf(c); h.w = f2bf(d);
    return h;
}

// ---------------- fp32 -> bf16 weight convert (5 matrices) --------------
__global__ __launch_bounds__(256) void wconv5_kernel(
    const float* __restrict__ a, const float* __restrict__ b,
    const float* __restrict__ c, const float* __restrict__ d,
    const float* __restrict__ e, unsigned short* __restrict__ o)
{
    int i = blockIdx.x * 256 + threadIdx.x;       // 5*16384 total
    int w = i >> 14, j = i & 16383;
    const float* p = (w == 0) ? a : (w == 1) ? b : (w == 2) ? c : (w == 3) ? d : e;
    o[i] = f2bf(p[j]);
}

// ================= kernel A: LN+GELU -> delta; dstr = delta + struc@Ws^T + bs
// 64-row tile, 4 waves; wave-private rows everywhere except Ws staging (3 barriers).
__global__ __launch_bounds__(256) void node_a_kernel(
    const float* __restrict__ in_feats, const float* __restrict__ struc,
    const float* __restrict__ gamma, const float* __restrict__ beta,
    const unsigned short* __restrict__ Wsb, const float* __restrict__ bs,
    unsigned short* __restrict__ deltab, unsigned short* __restrict__ dstrb, int M)
{
    __shared__ unsigned short Xd[64][136];    // delta (bf16)
    __shared__ unsigned short Xs2[64][136];   // struc -> dstr (bf16)
    __shared__ unsigned short Wl[64][136];    // Ws half

    int tid = threadIdx.x;
    int m0 = blockIdx.x * 64;
    int lane = tid & 63, w = tid >> 6, lg = lane & 15, quad = lane >> 4;

    // stage Ws half0 (cooperative)
    {
        const uint4* g = (const uint4*)Wsb;
        #pragma unroll
        for (int p = 0; p < 4; ++p) {
            int idx = tid + p * 256;
            *(uint4*)&Wl[idx >> 4][(idx & 15) * 8] = g[idx];
        }
    }
    // LN+GELU -> Xd ; struc -> Xs2  (4 threads/row, own-wave rows)
    {
        int row = tid >> 2, t4 = tid & 3;
        int gm = m0 + row;
        bool vr = gm < M;
        const float4* ip = (const float4*)(in_feats + (size_t)gm * NF) + t4 * 8;
        float4 xf[8];
        #pragma unroll
        for (int p = 0; p < 8; ++p)
            xf[p] = vr ? ip[p] : make_float4(0.f, 0.f, 0.f, 0.f);
        float s = 0.f, sq = 0.f;
        #pragma unroll
        for (int p = 0; p < 8; ++p) {
            s  += xf[p].x + xf[p].y + xf[p].z + xf[p].w;
            sq += xf[p].x * xf[p].x + xf[p].y * xf[p].y
                + xf[p].z * xf[p].z + xf[p].w * xf[p].w;
        }
        s  += __shfl_xor(s, 1, 64);  s  += __shfl_xor(s, 2, 64);
        sq += __shfl_xor(sq, 1, 64); sq += __shfl_xor(sq, 2, 64);
        float mu = s * (1.0f / 128.0f);
        float var = sq * (1.0f / 128.0f) - mu * mu;
        float rstd = rsqrtf(var + 1e-5f);
        const float4* gp = (const float4*)gamma + t4 * 8;
        const float4* bp = (const float4*)beta + t4 * 8;
        #pragma unroll
        for (int p = 0; p < 8; ++p) {
            float4 g4 = gp[p], b4 = bp[p];
            float o0 = (xf[p].x - mu) * rstd * g4.x + b4.x;
            float o1 = (xf[p].y - mu) * rstd * g4.y + b4.y;
            float o2 = (xf[p].z - mu) * rstd * g4.z + b4.z;
            float o3 = (xf[p].w - mu) * rstd * g4.w + b4.w;
            o0 = 0.5f * o0 * (1.0f + erff(o0 * 0.70710678118654752f));
            o1 = 0.5f * o1 * (1.0f + erff(o1 * 0.70710678118654752f));
            o2 = 0.5f * o2 * (1.0f + erff(o2 * 0.70710678118654752f));
            o3 = 0.5f * o3 * (1.0f + erff(o3 * 0.70710678118654752f));
            *(ushort4*)&Xd[row][t4 * 32 + p * 4] = pack4(o0, o1, o2, o3);
        }
        const float4* sp = (const float4*)(struc + (size_t)gm * NF) + t4 * 8;
        #pragma unroll
        for (int p = 0; p < 8; ++p) {
            float4 f = vr ? sp[p] : make_float4(0.f, 0.f, 0.f, 0.f);
            *(ushort4*)&Xs2[row][t4 * 32 + p * 4] = pack4(f.x, f.y, f.z, f.w);
        }
    }
    __syncthreads();   // #1: Wl h0 + Xs2 ready

    floatx4 acc[8];
    #pragma unroll
    for (int t = 0; t < 8; ++t) acc[t] = (floatx4){0.f, 0.f, 0.f, 0.f};

    #pragma unroll
    for (int ks = 0; ks < 4; ++ks) {
        short8 a = *(const short8*)&Xs2[w * 16 + lg][ks * 32 + quad * 8];
        #pragma unroll
        for (int t = 0; t < 4; ++t) {
            short8 b = *(const short8*)&Wl[t * 16 + lg][ks * 32 + quad * 8];
            acc[t] = __builtin_amdgcn_mfma_f32_16x16x32_bf16(a, b, acc[t], 0, 0, 0);
        }
    }
    __syncthreads();   // #2: h0 reads done
    {
        const uint4* g = (const uint4*)(Wsb + 8192);
        #pragma unroll
        for (int p = 0; p < 4; ++p) {
            int idx = tid + p * 256;
            *(uint4*)&Wl[idx >> 4][(idx & 15) * 8] = g[idx];
        }
    }
    __syncthreads();   // #3: h1 ready
    #pragma unroll
    for (int ks = 0; ks < 4; ++ks) {
        short8 a = *(const short8*)&Xs2[w * 16 + lg][ks * 32 + quad * 8];
        #pragma unroll
        for (int t = 0; t < 4; ++t) {
            short8 b = *(const short8*)&Wl[t * 16 + lg][ks * 32 + quad * 8];
            acc[4 + t] = __builtin_amdgcn_mfma_f32_16x16x32_bf16(a, b, acc[4 + t], 0, 0, 0);
        }
    }

    // dstr writeback into Xs2 (own-wave rows; no barrier needed)
    #pragma unroll
    for (int t = 0; t < 8; ++t) {
        int col = t * 16 + lg;
        float bvv = bs[col];
        #pragma unroll
        for (int r = 0; r < 4; ++r) {
            int rl = w * 16 + quad * 4 + r;
            Xs2[rl][col] = f2bf(acc[t][r] + bvv + bf2f(Xd[rl][col]));
        }
    }
    // copy out own-wave rows (coalesced uint4)
    #pragma unroll
    for (int p = 0; p < 4; ++p) {
        int idx = lane + p * 64;            // 256 uint4 = 16 rows x 16
        int row = w * 16 + (idx >> 4), c16 = idx & 15;
        int gm = m0 + row;
        if (gm < M) {
            *(uint4*)(deltab + (size_t)gm * NF + c16 * 8) = *(const uint4*)&Xd[row][c16 * 8];
            *(uint4*)(dstrb  + (size_t)gm * NF + c16 * 8) = *(const uint4*)&Xs2[row][c16 * 8];
        }
    }
}

// ================= kernel BCD: q/k/v GEMMs, blockIdx.y selects output ====
// 1 barrier per block; epilogue stages C into dead X buffer (own rows).
__global__ __launch_bounds__(256) void node_qkv_kernel(
    const unsigned short* __restrict__ deltab, const unsigned short* __restrict__ dstrb,
    const unsigned short* __restrict__ Wall, const float* __restrict__ bq,
    const float* __restrict__ bk, const float* __restrict__ bv,
    unsigned short* __restrict__ qb, unsigned short* __restrict__ kb,
    unsigned short* __restrict__ vb, int M)
{
    __shared__ unsigned short Xs[64][136];
    __shared__ unsigned short Wl[128][136];

    int tid = threadIdx.x;
    int m0 = blockIdx.x * 64;
    int y = blockIdx.y;                      // 0=q 1=k 2=v
    int lane = tid & 63, w = tid >> 6, lg = lane & 15, quad = lane >> 4;

    const unsigned short* Xg = (y == 2) ? deltab : dstrb;
    const unsigned short* Wg = Wall + (y + 1) * 16384;   // Wq,Wk,Wv
    const float* bias = (y == 0) ? bq : (y == 1) ? bk : bv;
    float scale = (y == 0) ? 0.25f : 1.0f;
    unsigned short* outg = (y == 0) ? qb : (y == 1) ? kb : vb;

    // stage W full (cooperative)
    {
        const uint4* g = (const uint4*)Wg;
        #pragma unroll
        for (int p = 0; p < 8; ++p) {
            int idx = tid + p * 256;
            *(uint4*)&Wl[idx >> 4][(idx & 15) * 8] = g[idx];
        }
    }
    // stage X own-wave rows (coalesced: 16 rows = 4KB contiguous per wave)
    {
        const uint4* X = (const uint4*)Xg;
        #pragma unroll
        for (int p = 0; p < 4; ++p) {
            int idx = lane + p * 64;
            int row = w * 16 + (idx >> 4), c16 = idx & 15;
            int gm = m0 + row;
            uint4 u = make_uint4(0u, 0u, 0u, 0u);
            if (gm < M) u = X[(size_t)gm * 16 + c16];
            *(uint4*)&Xs[row][c16 * 8] = u;
        }
    }
    __syncthreads();   // the only barrier

    floatx4 acc[8];
    #pragma unroll
    for (int t = 0; t < 8; ++t) acc[t] = (floatx4){0.f, 0.f, 0.f, 0.f};
    #pragma unroll
    for (int ks = 0; ks < 4; ++ks) {
        short8 a = *(const short8*)&Xs[w * 16 + lg][ks * 32 + quad * 8];
        #pragma unroll
        for (int t = 0; t < 8; ++t) {
            short8 b = *(const short8*)&Wl[t * 16 + lg][ks * 32 + quad * 8];
            acc[t] = __builtin_amdgcn_mfma_f32_16x16x32_bf16(a, b, acc[t], 0, 0, 0);
        }
    }

    // epilogue: bias+scale, stage into own-wave Xs rows, coalesced copy out
    #pragma unroll
    for (int t = 0; t < 8; ++t) {
        int col = t * 16 + lg;
        float bvv = bias[col];
        #pragma unroll
        for (int r = 0; r < 4; ++r)
            Xs[w * 16 + quad * 4 + r][col] = f2bf((acc[t][r] + bvv) * scale);
    }
    #pragma unroll
    for (int p = 0; p < 4; ++p) {
        int idx = lane + p * 64;
        int row = w * 16 + (idx >> 4), c16 = idx & 15;
        int gm = m0 + row;
        if (gm < M)
            *(uint4*)(outg + (size_t)gm * NF + c16 * 8) = *(const uint4*)&Xs[row][c16 * 8];
    }
}

// ---------------- out-proj GEMM: out = in_feats + agg @ Wo^T ----------
__global__ __launch_bounds__(256) void gemm_out_kernel(
    const unsigned short* __restrict__ Xb, const unsigned short* __restrict__ Wb,
    const float* __restrict__ addf, float* __restrict__ Y, int M)
{
    __shared__ unsigned short Xs[64][136];
    __shared__ unsigned short Wl[128][136];
    int tid = threadIdx.x;
    int m0 = blockIdx.x * 64;
    int lane = tid & 63, w = tid >> 6, lg = lane & 15, quad = lane >> 4;

    {
        const uint4* g = (const uint4*)Wb;
        #pragma unroll
        for (int p = 0; p < 8; ++p) {
            int idx = tid + p * 256;
            *(uint4*)&Wl[idx >> 4][(idx & 15) * 8] = g[idx];
        }
    }
    {
        const uint4* X = (const uint4*)Xb;
        #pragma unroll
        for (int p = 0; p < 4; ++p) {
            int idx = lane + p * 64;
            int row = w * 16 + (idx >> 4), c16 = idx & 15;
            int gm = m0 + row;
            uint4 u = make_uint4(0u, 0u, 0u, 0u);
            if (gm < M) u = X[(size_t)gm * 16 + c16];
            *(uint4*)&Xs[row][c16 * 8] = u;
        }
    }
    __syncthreads();

    floatx4 acc[8];
    #pragma unroll
    for (int t = 0; t < 8; ++t) acc[t] = (floatx4){0.f, 0.f, 0.f, 0.f};
    #pragma unroll
    for (int ks = 0; ks < 4; ++ks) {
        short8 a = *(const short8*)&Xs[w * 16 + lg][ks * 32 + quad * 8];
        #pragma unroll
        for (int t = 0; t < 8; ++t) {
            short8 b = *(const short8*)&Wl[t * 16 + lg][ks * 32 + quad * 8];
            acc[t] = __builtin_amdgcn_mfma_f32_16x16x32_bf16(a, b, acc[t], 0, 0, 0);
        }
    }
    // direct fp32 epilogue: 16 lanes -> 64B contiguous per (t,r)
    #pragma unroll
    for (int t = 0; t < 8; ++t) {
        int col = t * 16 + lg;
        #pragma unroll
        for (int r = 0; r < 4; ++r) {
            int gm = m0 + w * 16 + quad * 4 + r;
            if (gm >= M) continue;
            size_t off = (size_t)gm * NF + col;
            Y[off] = acc[t][r] + addf[off];
        }
    }
}

// ---------------- CSR build ----------------
__global__ void hist_kernel(const int* __restrict__ eid, int* __restrict__ cnt, int E)
{
    int i = blockIdx.x * blockDim.x + threadIdx.x;
    if (i < E) atomicAdd(&cnt[eid[i]], 1);
}

__global__ __launch_bounds__(256) void scan1_kernel(
    const int* __restrict__ cnt, int* __restrict__ bsum, int n)
{
    int base = blockIdx.x * 1024;
    int s = 0;
    #pragma unroll
    for (int p = 0; p < 4; ++p) {
        int i = base + (int)threadIdx.x + p * 256;
        if (i < n) s += cnt[i];
    }
    #pragma unroll
    for (int m = 1; m <= 32; m <<= 1) s += __shfl_xor(s, m, 64);
    __shared__ int ws_[4];
    int wid = threadIdx.x >> 6;
    if ((threadIdx.x & 63) == 0) ws_[wid] = s;
    __syncthreads();
    if (threadIdx.x == 0) bsum[blockIdx.x] = ws_[0] + ws_[1] + ws_[2] + ws_[3];
}

// rescan each chunk; block prefix computed inline from bsum (nb<=64)
__global__ __launch_bounds__(256) void scan3_kernel(
    const int* __restrict__ cnt, const int* __restrict__ bsum,
    int* __restrict__ row_start, int* __restrict__ cursor, int n, int nb)
{
    __shared__ int base_off;
    int tid = threadIdx.x, lane = tid & 63, wid = tid >> 6;
    if (tid == 0) {
        int a = 0;
        for (int j = 0; j < (int)blockIdx.x; ++j) a += bsum[j];
        base_off = a;
        if ((int)blockIdx.x == nb - 1) {
            int tot = a;
            for (int j = blockIdx.x; j < nb; ++j) tot += bsum[j];
            row_start[n] = tot;
        }
    }
    int base = blockIdx.x * 1024;
    int v[4]; int s = 0;
    #pragma unroll
    for (int p = 0; p < 4; ++p) {
        int i = base + tid * 4 + p;
        v[p] = (i < n) ? cnt[i] : 0;
        s += v[p];
    }
    int ss = s;
    #pragma unroll
    for (int off = 1; off < 64; off <<= 1) {
        int t = __shfl_up(ss, off, 64);
        if (lane >= off) ss += t;
    }
    __shared__ int wsum[4];
    if (lane == 63) wsum[wid] = ss;
    __syncthreads();
    int woff = 0;
    for (int j = 0; j < wid; ++j) woff += wsum[j];
    int a = base_off + woff + (ss - s);
    #pragma unroll
    for (int p = 0; p < 4; ++p) {
        int i = base + tid * 4 + p;
        if (i < n) { row_start[i] = a; cursor[i] = a; a += v[p]; }
    }
}

__global__ void scatter_kernel(const int* __restrict__ eid, const float* __restrict__ ew,
                               int* __restrict__ cursor, int2* __restrict__ edata, int E)
{
    int i = blockIdx.x * blockDim.x + threadIdx.x;
    if (i < E) {
        int src = eid[i];
        int dst = eid[E + i];
        int pos = atomicAdd(&cursor[src], 1);
        edata[pos] = make_int2(dst, __float_as_int(ew[i]));
    }
}

// ---------------- per-node attention aggregation ----------------
// 256-thr block = 4 nodes (1 wave each); 2 edges/subgroup/iter + prefetch
__global__ __launch_bounds__(256) void aggregate_kernel(
    const unsigned short* __restrict__ Q, const unsigned short* __restrict__ Kf,
    const unsigned short* __restrict__ V, const int* __restrict__ row_start,
    const int2* __restrict__ edata, unsigned short* __restrict__ agg, int N)
{
    int node = blockIdx.x * 4 + (threadIdx.x >> 6);
    if (node >= N) return;
    int lane = threadIdx.x & 63;
    int sg = lane >> 4, lg = lane & 15;
    int rs = row_start[node], re = row_start[node + 1];

    float qv[8];
    unpack8(*(const uint4*)(Q + (size_t)node * NF + lg * 8), qv);
    float acc[8];
    #pragma unroll
    for (int j = 0; j < 8; ++j) acc[j] = 0.f;

    int e1 = rs + sg, e2 = rs + sg + 4;
    int2 ed1 = (e1 < re) ? edata[e1] : make_int2(0, 0);
    int2 ed2 = (e2 < re) ? edata[e2] : make_int2(0, 0);

    for (int e0 = rs; e0 < re; e0 += 8) {
        int2 c1 = ed1, c2 = ed2;
        int en1 = e0 + 8 + sg, en2 = en1 + 4;
        ed1 = (en1 < re) ? edata[en1] : make_int2(0, 0);
        ed2 = (en2 < re) ? edata[en2] : make_int2(0, 0);

        float kv1[8], kv2[8];
        unpack8(*(const uint4*)(Kf + (size_t)c1.x * NF + lg * 8), kv1);
        unpack8(*(const uint4*)(Kf + (size_t)c2.x * NF + lg * 8), kv2);
        float s1 = qv[0] * kv1[0], s2 = qv[0] * kv2[0];
        #pragma unroll
        for (int j = 1; j < 8; ++j) {
            s1 = fmaf(qv[j], kv1[j], s1);
            s2 = fmaf(qv[j], kv2[j], s2);
        }
        s1 += __shfl_xor(s1, 1, 64);    // head = 16 feats = 2 adjacent lanes
        s2 += __shfl_xor(s2, 1, 64);
        float a1 = __int_as_float(c1.y) / (1.f + __expf(-s1));
        float a2 = __int_as_float(c2.y) / (1.f + __expf(-s2));

        float vv1[8], vv2[8];
        unpack8(*(const uint4*)(V + (size_t)c1.x * NF + lg * 8), vv1);
        unpack8(*(const uint4*)(V + (size_t)c2.x * NF + lg * 8), vv2);
        #pragma unroll
        for (int j = 0; j < 8; ++j) {
            acc[j] = fmaf(a1, vv1[j], acc[j]);
            acc[j] = fmaf(a2, vv2[j], acc[j]);
        }
    }
    #pragma unroll
    for (int j = 0; j < 8; ++j) {
        acc[j] += __shfl_xor(acc[j], 16, 64);
        acc[j] += __shfl_xor(acc[j], 32, 64);
    }
    if (sg == 0) {
        unsigned short* o = agg + (size_t)node * NF + lg * 8;
        *(ushort4*)o       = pack4(acc[0], acc[1], acc[2], acc[3]);
        *(ushort4*)(o + 4) = pack4(acc[4], acc[5], acc[6], acc[7]);
    }
}

extern "C" void kernel_launch(void* const* d_in, const int* in_sizes, int n_in,
                              void* d_out, int out_size, void* d_ws, size_t ws_size,
                              hipStream_t stream)
{
    const float* in_feats = (const float*)d_in[0];
    const float* struc    = (const float*)d_in[1];
    const float* eweights = (const float*)d_in[2];
    const float* ln_scale = (const float*)d_in[3];
    const float* ln_bias  = (const float*)d_in[4];
    const float* Ws       = (const float*)d_in[5];
    const float* bs       = (const float*)d_in[6];
    const float* Wq       = (const float*)d_in[7];
    const float* bq       = (const float*)d_in[8];
    const float* Wk       = (const float*)d_in[9];
    const float* bk       = (const float*)d_in[10];
    const float* Wv       = (const float*)d_in[11];
    const float* bv       = (const float*)d_in[12];
    const float* Wo       = (const float*)d_in[13];
    const int*   edge_ids = (const int*)d_in[14];
    float* out = (float*)d_out;

    int N = in_sizes[0] / NF;   // 50000
    int E = in_sizes[2];        // 800000

    // ---- workspace
    size_t F = (size_t)N * NF;
    unsigned short* deltab = (unsigned short*)d_ws;
    unsigned short* dstrb  = deltab + F;
    unsigned short* qb     = dstrb + F;
    unsigned short* kb     = qb + F;
    unsigned short* vb     = kb + F;
    unsigned short* aggb   = vb + F;
    unsigned short* Wall   = aggb + F;          // 5*16384: Ws,Wq,Wk,Wv,Wo
    int2*  edata     = (int2*)(Wall + 5 * 16384);
    int*   cnt       = (int*)(edata + E);
    int*   row_start = cnt + N;                 // N+1
    int*   cursor    = row_start + N + 1;
    int*   bsum      = cursor + N;              // 64

    int gb  = (N + 63) / 64;
    int geb = (E + 255) / 256;
    int nb  = (N + 1023) / 1024;

    // weights -> bf16
    wconv5_kernel<<<(5 * 16384) / 256, 256, 0, stream>>>(Ws, Wq, Wk, Wv, Wo, Wall);

    // CSR build by src
    hipMemsetAsync(cnt, 0, (size_t)N * sizeof(int), stream);
    hist_kernel<<<geb, 256, 0, stream>>>(edge_ids, cnt, E);
    scan1_kernel<<<nb, 256, 0, stream>>>(cnt, bsum, N);
    scan3_kernel<<<nb, 256, 0, stream>>>(cnt, bsum, row_start, cursor, N, nb);
    scatter_kernel<<<geb, 256, 0, stream>>>(edge_ids, eweights, cursor, edata, E);

    // node transforms
    node_a_kernel<<<gb, 256, 0, stream>>>(in_feats, struc, ln_scale, ln_bias,
                                          Wall, bs, deltab, dstrb, N);
    node_qkv_kernel<<<dim3(gb, 3), 256, 0, stream>>>(deltab, dstrb, Wall,
                                                     bq, bk, bv, qb, kb, vb, N);

    // edge attention + segment-sum
    aggregate_kernel<<<(N + 3) / 4, 256, 0, stream>>>(qb, kb, vb, row_start, edata, aggb, N);

    // out = in_feats + agg @ Wo^T
    gemm_out_kernel<<<gb, 256, 0, stream>>>(aggb, Wall + 4 * 16384, in_feats, out, N);
}

// Round 5
// 326.064 us; speedup vs baseline: 1.0350x; 1.0350x over previous
//
#include <hip/hip_runtime.h>
#include <math.h>

#define NF 128

typedef __attribute__((ext_vector_type(8))) short short8;
typedef __attribute__((ext_vector_type(4))) float floatx4;

__device__ __forceinline__ unsigned short f2bf(float f) {
    union { float x; unsigned int i; } c; c.x = f;
    unsigned int r = c.i + 0x7fffu + ((c.i >> 16) & 1u);   // RNE
    return (unsigned short)(r >> 16);
}
__device__ __forceinline__ float bf2f(unsigned short u) {
    union { unsigned int i; float x; } c; c.i = ((unsigned int)u) << 16;
    return c.x;
}
__device__ __forceinline__ void unpack8(uint4 u, float* f) {
    union { unsigned int i; float x; } c;
    c.i = u.x << 16;          f[0] = c.x;
    c.i = u.x & 0xffff0000u;  f[1] = c.x;
    c.i = u.y << 16;          f[2] = c.x;
    c.i = u.y & 0xffff0000u;  f[3] = c.x;
    c.i = u.z << 16;          f[4] = c.x;
    c.i = u.z & 0xffff0000u;  f[5] = c.x;
    c.i = u.w << 16;          f[6] = c.x;
    c.i = u.w & 0xffff0000u;  f[7] = c.x;
}
__device__ __forceinline__ ushort4 pack4(float a, float b, float c, float d) {
    ushort4 h; h.x = f2bf(a); h.y = f2bf(b); h.z = f2bf(c); h.w = f2bf(d);
    return h;
}

// ---------------- fp32 -> bf16 weight convert (5 matrices) --------------
__global__ __launch_bounds__(256) void wconv5_kernel(
    const float* __restrict__ a, const float* __restrict__ b,
    const float* __restrict__ c, const float* __restrict__ d,
    const float* __restrict__ e, unsigned short* __restrict__ o)
{
    int i = blockIdx.x * 256 + threadIdx.x;       // 5*16384 total
    int w = i >> 14, j = i & 16383;
    const float* p = (w == 0) ? a : (w == 1) ? b : (w == 2) ? c : (w == 3) ? d : e;
    o[i] = f2bf(p[j]);
}

// ================= node_a: LN+GELU -> delta; dstr = delta + struc@Ws^T + bs
// W staged once; grid-stride over 64-row tiles; ZERO barriers in loop.
__global__ __launch_bounds__(256) void node_a_kernel(
    const float* __restrict__ in_feats, const float* __restrict__ struc,
    const float* __restrict__ gamma, const float* __restrict__ beta,
    const unsigned short* __restrict__ Wsb, const float* __restrict__ bs,
    unsigned short* __restrict__ deltab, unsigned short* __restrict__ dstrb,
    int M, int nt)
{
    __shared__ unsigned short Wl[128][136];
    __shared__ unsigned short Xs2[64][136];

    int tid = threadIdx.x;
    int lane = tid & 63, w = tid >> 6, lg = lane & 15, quad = lane >> 4;
    int lrow = tid >> 2, t4 = tid & 3;        // LN mapping: 4 thr/row (wave-private rows)

    {   // stage full Ws (32KB) — the only barrier
        const uint4* g = (const uint4*)Wsb;
        #pragma unroll
        for (int p = 0; p < 8; ++p) {
            int idx = tid + p * 256;
            *(uint4*)&Wl[idx >> 4][(idx & 15) * 8] = g[idx];
        }
    }
    // bias regs (col = t*16+lg)
    float bsr[8];
    #pragma unroll
    for (int t = 0; t < 8; ++t) bsr[t] = bs[t * 16 + lg];
    __syncthreads();

    for (int tile = blockIdx.x; tile < nt; tile += gridDim.x) {
        int m0 = tile * 64;
        int gm = m0 + lrow;
        bool vr = gm < M;
        size_t rbase = (size_t)(vr ? gm : 0) * NF;

        // ---- LN + GELU -> delta regs; write delta to global
        uint dreg[16];   // 32 bf16 (cols t4*32..+32)
        {
            const float4* ip = (const float4*)(in_feats + rbase) + t4 * 8;
            float4 xf[8];
            #pragma unroll
            for (int p = 0; p < 8; ++p) xf[p] = ip[p];
            float s = 0.f, sq = 0.f;
            #pragma unroll
            for (int p = 0; p < 8; ++p) {
                s  += xf[p].x + xf[p].y + xf[p].z + xf[p].w;
                sq += xf[p].x * xf[p].x + xf[p].y * xf[p].y
                    + xf[p].z * xf[p].z + xf[p].w * xf[p].w;
            }
            s  += __shfl_xor(s, 1, 64);  s  += __shfl_xor(s, 2, 64);
            sq += __shfl_xor(sq, 1, 64); sq += __shfl_xor(sq, 2, 64);
            float mu = s * (1.0f / 128.0f);
            float var = sq * (1.0f / 128.0f) - mu * mu;
            float rstd = rsqrtf(var + 1e-5f);
            const float4* gp = (const float4*)gamma + t4 * 8;
            const float4* bp = (const float4*)beta + t4 * 8;
            #pragma unroll
            for (int p = 0; p < 8; ++p) {
                float4 g4 = gp[p], b4 = bp[p];
                float o0 = (xf[p].x - mu) * rstd * g4.x + b4.x;
                float o1 = (xf[p].y - mu) * rstd * g4.y + b4.y;
                float o2 = (xf[p].z - mu) * rstd * g4.z + b4.z;
                float o3 = (xf[p].w - mu) * rstd * g4.w + b4.w;
                o0 = 0.5f * o0 * (1.0f + erff(o0 * 0.70710678118654752f));
                o1 = 0.5f * o1 * (1.0f + erff(o1 * 0.70710678118654752f));
                o2 = 0.5f * o2 * (1.0f + erff(o2 * 0.70710678118654752f));
                o3 = 0.5f * o3 * (1.0f + erff(o3 * 0.70710678118654752f));
                ushort4 h = pack4(o0, o1, o2, o3);
                dreg[p * 2]     = (uint)h.x | ((uint)h.y << 16);
                dreg[p * 2 + 1] = (uint)h.z | ((uint)h.w << 16);
            }
            if (vr) {
                uint4* od = (uint4*)(deltab + (size_t)gm * NF + t4 * 32);
                #pragma unroll
                for (int q = 0; q < 4; ++q)
                    od[q] = make_uint4(dreg[q*4], dreg[q*4+1], dreg[q*4+2], dreg[q*4+3]);
            }
            // struc -> Xs2 (own-wave rows)
            const float4* sp = (const float4*)(struc + rbase) + t4 * 8;
            #pragma unroll
            for (int p = 0; p < 8; ++p) {
                float4 f = sp[p];
                *(ushort4*)&Xs2[lrow][t4 * 32 + p * 4] = pack4(f.x, f.y, f.z, f.w);
            }
        }

        // ---- MFMA: struc @ Ws^T
        floatx4 acc[8];
        #pragma unroll
        for (int t = 0; t < 8; ++t) acc[t] = (floatx4){0.f, 0.f, 0.f, 0.f};
        #pragma unroll
        for (int ks = 0; ks < 4; ++ks) {
            short8 a = *(const short8*)&Xs2[w * 16 + lg][ks * 32 + quad * 8];
            #pragma unroll
            for (int t = 0; t < 8; ++t) {
                short8 b = *(const short8*)&Wl[t * 16 + lg][ks * 32 + quad * 8];
                acc[t] = __builtin_amdgcn_mfma_f32_16x16x32_bf16(a, b, acc[t], 0, 0, 0);
            }
        }

        // ---- Xs2 dead -> overwrite with delta (own rows, LN layout)
        #pragma unroll
        for (int q = 0; q < 4; ++q)
            *(uint4*)&Xs2[lrow][t4 * 32 + q * 8] =
                make_uint4(dreg[q*4], dreg[q*4+1], dreg[q*4+2], dreg[q*4+3]);

        // ---- dstr = acc + bs + delta, in-place (single reader=writer per elem)
        #pragma unroll
        for (int t = 0; t < 8; ++t) {
            int col = t * 16 + lg;
            #pragma unroll
            for (int r = 0; r < 4; ++r) {
                int rl = w * 16 + quad * 4 + r;
                Xs2[rl][col] = f2bf(acc[t][r] + bsr[t] + bf2f(Xs2[rl][col]));
            }
        }
        // ---- copy out dstr (own-wave rows, coalesced)
        #pragma unroll
        for (int p = 0; p < 4; ++p) {
            int idx = lane + p * 64;
            int row = w * 16 + (idx >> 4), c16 = idx & 15;
            int gmo = m0 + row;
            if (gmo < M)
                *(uint4*)(dstrb + (size_t)gmo * NF + c16 * 8) = *(const uint4*)&Xs2[row][c16 * 8];
        }
    }
}

// ================= node_qkv: q/k/v GEMMs; W once; A-frags direct from global
__global__ __launch_bounds__(256) void node_qkv_kernel(
    const unsigned short* __restrict__ deltab, const unsigned short* __restrict__ dstrb,
    const unsigned short* __restrict__ Wall, const float* __restrict__ bq,
    const float* __restrict__ bk, const float* __restrict__ bv,
    unsigned short* __restrict__ qb, unsigned short* __restrict__ kvb,
    int M, int nt)
{
    __shared__ unsigned short Wl[128][136];
    __shared__ unsigned short Cst[64][136];

    int tid = threadIdx.x;
    int y = blockIdx.y;                       // 0=q 1=k 2=v
    int lane = tid & 63, w = tid >> 6, lg = lane & 15, quad = lane >> 4;

    const unsigned short* Xg = (y == 2) ? deltab : dstrb;
    const unsigned short* Wg = Wall + (y + 1) * 16384;
    const float* bias = (y == 0) ? bq : (y == 1) ? bk : bv;
    float scale = (y == 0) ? 0.25f : 1.0f;
    unsigned short* outg = (y == 0) ? qb : (y == 1) ? kvb : (kvb + NF);
    int ostride = (y == 0) ? NF : 2 * NF;

    {
        const uint4* g = (const uint4*)Wg;
        #pragma unroll
        for (int p = 0; p < 8; ++p) {
            int idx = tid + p * 256;
            *(uint4*)&Wl[idx >> 4][(idx & 15) * 8] = g[idx];
        }
    }
    float br[8];
    #pragma unroll
    for (int t = 0; t < 8; ++t) br[t] = bias[t * 16 + lg] * scale;
    __syncthreads();   // the only barrier

    for (int tile = blockIdx.x; tile < nt; tile += gridDim.x) {
        int m0 = tile * 64;
        int am = m0 + w * 16 + lg;
        const unsigned short* arow = Xg + (size_t)(am < M ? am : 0) * NF + quad * 8;

        floatx4 acc[8];
        #pragma unroll
        for (int t = 0; t < 8; ++t) acc[t] = (floatx4){0.f, 0.f, 0.f, 0.f};
        short8 af[4];
        #pragma unroll
        for (int ks = 0; ks < 4; ++ks) af[ks] = *(const short8*)(arow + ks * 32);
        #pragma unroll
        for (int ks = 0; ks < 4; ++ks) {
            #pragma unroll
            for (int t = 0; t < 8; ++t) {
                short8 b = *(const short8*)&Wl[t * 16 + lg][ks * 32 + quad * 8];
                acc[t] = __builtin_amdgcn_mfma_f32_16x16x32_bf16(af[ks], b, acc[t], 0, 0, 0);
            }
        }
        // epilogue: stage into own-wave Cst rows, coalesced copy out
        #pragma unroll
        for (int t = 0; t < 8; ++t) {
            int col = t * 16 + lg;
            #pragma unroll
            for (int r = 0; r < 4; ++r)
                Cst[w * 16 + quad * 4 + r][col] = f2bf(acc[t][r] * scale + br[t]);
        }
        #pragma unroll
        for (int p = 0; p < 4; ++p) {
            int idx = lane + p * 64;
            int row = w * 16 + (idx >> 4), c16 = idx & 15;
            int gm = m0 + row;
            if (gm < M)
                *(uint4*)(outg + (size_t)gm * ostride + c16 * 8) = *(const uint4*)&Cst[row][c16 * 8];
        }
    }
}

// ================= out-proj: out = in_feats + agg @ Wo^T =================
__global__ __launch_bounds__(256) void gemm_out_kernel(
    const unsigned short* __restrict__ Xb, const unsigned short* __restrict__ Wb,
    const float* __restrict__ addf, float* __restrict__ Y, int M, int nt)
{
    __shared__ unsigned short Wl[128][136];
    int tid = threadIdx.x;
    int lane = tid & 63, w = tid >> 6, lg = lane & 15, quad = lane >> 4;

    {
        const uint4* g = (const uint4*)Wb;
        #pragma unroll
        for (int p = 0; p < 8; ++p) {
            int idx = tid + p * 256;
            *(uint4*)&Wl[idx >> 4][(idx & 15) * 8] = g[idx];
        }
    }
    __syncthreads();

    for (int tile = blockIdx.x; tile < nt; tile += gridDim.x) {
        int m0 = tile * 64;
        int am = m0 + w * 16 + lg;
        const unsigned short* arow = Xb + (size_t)(am < M ? am : 0) * NF + quad * 8;

        floatx4 acc[8];
        #pragma unroll
        for (int t = 0; t < 8; ++t) acc[t] = (floatx4){0.f, 0.f, 0.f, 0.f};
        short8 af[4];
        #pragma unroll
        for (int ks = 0; ks < 4; ++ks) af[ks] = *(const short8*)(arow + ks * 32);
        #pragma unroll
        for (int ks = 0; ks < 4; ++ks) {
            #pragma unroll
            for (int t = 0; t < 8; ++t) {
                short8 b = *(const short8*)&Wl[t * 16 + lg][ks * 32 + quad * 8];
                acc[t] = __builtin_amdgcn_mfma_f32_16x16x32_bf16(af[ks], b, acc[t], 0, 0, 0);
            }
        }
        // fp32 epilogue: per (t,r) 16 lanes write 64B contiguous
        #pragma unroll
        for (int t = 0; t < 8; ++t) {
            int col = t * 16 + lg;
            #pragma unroll
            for (int r = 0; r < 4; ++r) {
                int gm = m0 + w * 16 + quad * 4 + r;
                if (gm >= M) continue;
                size_t off = (size_t)gm * NF + col;
                Y[off] = acc[t][r] + addf[off];
            }
        }
    }
}

// ---------------- CSR build ----------------
__global__ void hist_kernel(const int* __restrict__ eid, int* __restrict__ cnt, int E)
{
    int i = blockIdx.x * blockDim.x + threadIdx.x;
    if (i < E) atomicAdd(&cnt[eid[i]], 1);
}

__global__ __launch_bounds__(256) void scan1_kernel(
    const int* __restrict__ cnt, int* __restrict__ bsum, int n)
{
    int base = blockIdx.x * 1024;
    int s = 0;
    #pragma unroll
    for (int p = 0; p < 4; ++p) {
        int i = base + (int)threadIdx.x + p * 256;
        if (i < n) s += cnt[i];
    }
    #pragma unroll
    for (int m = 1; m <= 32; m <<= 1) s += __shfl_xor(s, m, 64);
    __shared__ int ws_[4];
    int wid = threadIdx.x >> 6;
    if ((threadIdx.x & 63) == 0) ws_[wid] = s;
    __syncthreads();
    if (threadIdx.x == 0) bsum[blockIdx.x] = ws_[0] + ws_[1] + ws_[2] + ws_[3];
}

__global__ __launch_bounds__(256) void scan3_kernel(
    const int* __restrict__ cnt, const int* __restrict__ bsum,
    int* __restrict__ row_start, int* __restrict__ cursor, int n, int nb)
{
    __shared__ int base_off;
    int tid = threadIdx.x, lane = tid & 63, wid = tid >> 6;
    if (tid == 0) {
        int a = 0;
        for (int j = 0; j < (int)blockIdx.x; ++j) a += bsum[j];
        base_off = a;
        if ((int)blockIdx.x == nb - 1) {
            int tot = a;
            for (int j = blockIdx.x; j < nb; ++j) tot += bsum[j];
            row_start[n] = tot;
        }
    }
    int base = blockIdx.x * 1024;
    int v[4]; int s = 0;
    #pragma unroll
    for (int p = 0; p < 4; ++p) {
        int i = base + tid * 4 + p;
        v[p] = (i < n) ? cnt[i] : 0;
        s += v[p];
    }
    int ss = s;
    #pragma unroll
    for (int off = 1; off < 64; off <<= 1) {
        int t = __shfl_up(ss, off, 64);
        if (lane >= off) ss += t;
    }
    __shared__ int wsum[4];
    if (lane == 63) wsum[wid] = ss;
    __syncthreads();
    int woff = 0;
    for (int j = 0; j < wid; ++j) woff += wsum[j];
    int a = base_off + woff + (ss - s);
    #pragma unroll
    for (int p = 0; p < 4; ++p) {
        int i = base + tid * 4 + p;
        if (i < n) { row_start[i] = a; cursor[i] = a; a += v[p]; }
    }
}

__global__ void scatter_kernel(const int* __restrict__ eid, const float* __restrict__ ew,
                               int* __restrict__ cursor, int2* __restrict__ edata, int E)
{
    int i = blockIdx.x * blockDim.x + threadIdx.x;
    if (i < E) {
        int src = eid[i];
        int dst = eid[E + i];
        int pos = atomicAdd(&cursor[src], 1);
        edata[pos] = make_int2(dst, __float_as_int(ew[i]));
    }
}

// ---------------- per-node attention aggregation ----------------
// 4 nodes/block (1 wave each); 8 edges/iter; all gathers issued before compute.
// kvb: per node 512B = [K row | V row] (bf16)
__global__ __launch_bounds__(256) void aggregate_kernel(
    const unsigned short* __restrict__ Q, const unsigned short* __restrict__ kvb,
    const int* __restrict__ row_start, const int2* __restrict__ edata,
    unsigned short* __restrict__ agg, int N)
{
    int node = blockIdx.x * 4 + (threadIdx.x >> 6);
    if (node >= N) return;
    int lane = threadIdx.x & 63;
    int sg = lane >> 4, lg = lane & 15;
    int rs = row_start[node], re = row_start[node + 1];

    float qv[8];
    unpack8(*(const uint4*)(Q + (size_t)node * NF + lg * 8), qv);
    float acc[8];
    #pragma unroll
    for (int j = 0; j < 8; ++j) acc[j] = 0.f;

    int e1 = rs + sg, e2 = rs + sg + 4;
    int2 ed1 = (e1 < re) ? edata[e1] : make_int2(0, 0);
    int2 ed2 = (e2 < re) ? edata[e2] : make_int2(0, 0);

    for (int e0 = rs; e0 < re; e0 += 8) {
        int2 c1 = ed1, c2 = ed2;
        int en1 = e0 + 8 + sg, en2 = en1 + 4;
        ed1 = (en1 < re) ? edata[en1] : make_int2(0, 0);
        ed2 = (en2 < re) ? edata[en2] : make_int2(0, 0);

        // issue all 4 gathers up front (K,V adjacent lines per edge)
        const uint4* p1 = (const uint4*)kvb + (size_t)c1.x * 32 + lg;
        const uint4* p2 = (const uint4*)kvb + (size_t)c2.x * 32 + lg;
        uint4 k1u = p1[0], v1u = p1[16];
        uint4 k2u = p2[0], v2u = p2[16];

        float kv1[8], kv2[8];
        unpack8(k1u, kv1);
        unpack8(k2u, kv2);
        float s1 = qv[0] * kv1[0], s2 = qv[0] * kv2[0];
        #pragma unroll
        for (int j = 1; j < 8; ++j) {
            s1 = fmaf(qv[j], kv1[j], s1);
            s2 = fmaf(qv[j], kv2[j], s2);
        }
        s1 += __shfl_xor(s1, 1, 64);    // head = 16 feats = 2 adjacent lanes
        s2 += __shfl_xor(s2, 1, 64);
        float a1 = __int_as_float(c1.y) / (1.f + __expf(-s1));
        float a2 = __int_as_float(c2.y) / (1.f + __expf(-s2));

        float vv1[8], vv2[8];
        unpack8(v1u, vv1);
        unpack8(v2u, vv2);
        #pragma unroll
        for (int j = 0; j < 8; ++j) {
            acc[j] = fmaf(a1, vv1[j], acc[j]);
            acc[j] = fmaf(a2, vv2[j], acc[j]);
        }
    }
    #pragma unroll
    for (int j = 0; j < 8; ++j) {
        acc[j] += __shfl_xor(acc[j], 16, 64);
        acc[j] += __shfl_xor(acc[j], 32, 64);
    }
    if (sg == 0) {
        unsigned short* o = agg + (size_t)node * NF + lg * 8;
        *(ushort4*)o       = pack4(acc[0], acc[1], acc[2], acc[3]);
        *(ushort4*)(o + 4) = pack4(acc[4], acc[5], acc[6], acc[7]);
    }
}

extern "C" void kernel_launch(void* const* d_in, const int* in_sizes, int n_in,
                              void* d_out, int out_size, void* d_ws, size_t ws_size,
                              hipStream_t stream)
{
    const float* in_feats = (const float*)d_in[0];
    const float* struc    = (const float*)d_in[1];
    const float* eweights = (const float*)d_in[2];
    const float* ln_scale = (const float*)d_in[3];
    const float* ln_bias  = (const float*)d_in[4];
    const float* Ws       = (const float*)d_in[5];
    const float* bs       = (const float*)d_in[6];
    const float* Wq       = (const float*)d_in[7];
    const float* bq       = (const float*)d_in[8];
    const float* Wk       = (const float*)d_in[9];
    const float* bk       = (const float*)d_in[10];
    const float* Wv       = (const float*)d_in[11];
    const float* bv       = (const float*)d_in[12];
    const float* Wo       = (const float*)d_in[13];
    const int*   edge_ids = (const int*)d_in[14];
    float* out = (float*)d_out;

    int N = in_sizes[0] / NF;   // 50000
    int E = in_sizes[2];        // 800000

    // ---- workspace
    size_t F = (size_t)N * NF;
    unsigned short* deltab = (unsigned short*)d_ws;
    unsigned short* dstrb  = deltab + F;
    unsigned short* qb     = dstrb + F;
    unsigned short* kvb    = qb + F;            // 2F: [K|V] interleaved per node
    unsigned short* aggb   = kvb + 2 * F;
    unsigned short* Wall   = aggb + F;          // 5*16384: Ws,Wq,Wk,Wv,Wo
    int2*  edata     = (int2*)(Wall + 5 * 16384);
    int*   cnt       = (int*)(edata + E);
    int*   row_start = cnt + N;                 // N+1
    int*   cursor    = row_start + N + 1;
    int*   bsum      = cursor + N;              // 64

    int nt  = (N + 63) / 64;    // 782 row-tiles
    int geb = (E + 255) / 256;
    int nb  = (N + 1023) / 1024;

    // weights -> bf16
    wconv5_kernel<<<(5 * 16384) / 256, 256, 0, stream>>>(Ws, Wq, Wk, Wv, Wo, Wall);

    // CSR build by src
    hipMemsetAsync(cnt, 0, (size_t)N * sizeof(int), stream);
    hist_kernel<<<geb, 256, 0, stream>>>(edge_ids, cnt, E);
    scan1_kernel<<<nb, 256, 0, stream>>>(cnt, bsum, N);
    scan3_kernel<<<nb, 256, 0, stream>>>(cnt, bsum, row_start, cursor, N, nb);
    scatter_kernel<<<geb, 256, 0, stream>>>(edge_ids, eweights, cursor, edata, E);

    // node transforms (grid-stride, W staged once, 1 barrier/block)
    node_a_kernel<<<392, 256, 0, stream>>>(in_feats, struc, ln_scale, ln_bias,
                                           Wall, bs, deltab, dstrb, N, nt);
    node_qkv_kernel<<<dim3(261, 3), 256, 0, stream>>>(deltab, dstrb, Wall,
                                                      bq, bk, bv, qb, kvb, N, nt);

    // edge attention + segment-sum
    aggregate_kernel<<<(N + 3) / 4, 256, 0, stream>>>(qb, kvb, row_start, edata, aggb, N);

    // out = in_feats + agg @ Wo^T
    gemm_out_kernel<<<392, 256, 0, stream>>>(aggb, Wall + 4 * 16384, in_feats, out, N, nt);
}